// Round 3
// baseline (949.206 us; speedup 1.0000x reference)
//
#include <hip/hip_runtime.h>

// Problem constants (match reference)
#define BATCH 8192
#define TSTEPS 200
#define FEAT 16
#define HID 32
#define GATES 128   // 4*HID, Keras order: i | f | cc | o
#define DOUT 60
#define WPB 4       // waves (= batch elements) per block; block = 256 threads

// NOTE: __builtin_amdgcn_cvt_pkrtz / __builtin_amdgcn_fdot2 use Clang's
// "half" ext-vector (__fp16), not _Float16 — typedef must match.
typedef __fp16 half2v __attribute__((ext_vector_type(2)));

__device__ __forceinline__ float fast_sigmoid(float v) {
    float e = __builtin_amdgcn_exp2f(v * -1.44269504088896340736f);
    return __builtin_amdgcn_rcpf(1.0f + e);
}

__device__ __forceinline__ half2v pkrtz(float a, float b) {
    return __builtin_amdgcn_cvt_pkrtz(a, b);
}

// Layout: one batch element per wave. Lane L owns gate columns L and L+64
// of the fused [48 x 128] weight matrix, stationary in VGPRs as f16x2 pairs
// (packed along K). x_t is wave-uniform (scalar loads). h is distributed as
// 16 f16x2 SGPRs via v_readlane each step — no LDS, no ds_read on the
// recurrent path. Gate math: v_dot2_f32_f16 (f16 mul, fp32 accumulate).
//   lane < 32 : accA = i_u,  accB = cc_u   (u = lane)
//   lane >= 32: accA = f_u,  accB = o_u    (u = lane-32)
__global__ __launch_bounds__(256, 6) void lstm_fused(
    const float* __restrict__ x,    // [B, T, F]
    const float* __restrict__ W,    // [F, 128]
    const float* __restrict__ U,    // [H, 128]
    const float* __restrict__ bg,   // [128]
    const float* __restrict__ W1,   // [H, 60]
    const float* __restrict__ b1,   // [60]
    const float* __restrict__ W2,   // [H, 60]
    const float* __restrict__ b2,   // [60]
    float* __restrict__ out)        // [2 * B * 60] (long || lat)
{
    const int lane = threadIdx.x & 63;
    const int wid  = threadIdx.x >> 6;
    const int b    = blockIdx.x * WPB + wid;   // one batch element per wave

    const int colA = lane;        // i (low half) / f (high half)
    const int colB = lane + 64;   // cc (low half) / o (high half)

    // ---- stationary packed weights (per-lane, f16x2 along K) ----
    half2v wW[2][FEAT / 2];   // W columns colA/colB, pairs (k, k+1)
    half2v wU[2][HID / 2];    // U columns colA/colB
    #pragma unroll
    for (int j = 0; j < FEAT / 2; j++) {
        wW[0][j] = pkrtz(W[(2 * j) * GATES + colA], W[(2 * j + 1) * GATES + colA]);
        wW[1][j] = pkrtz(W[(2 * j) * GATES + colB], W[(2 * j + 1) * GATES + colB]);
    }
    #pragma unroll
    for (int j = 0; j < HID / 2; j++) {
        wU[0][j] = pkrtz(U[(2 * j) * GATES + colA], U[(2 * j + 1) * GATES + colA]);
        wU[1][j] = pkrtz(U[(2 * j) * GATES + colB], U[(2 * j + 1) * GATES + colB]);
    }
    const float bA = bg[colA];
    const float bB = bg[colB];

    // ---- state: c per-lane fp32 (valid in low lanes), h as 16 uniform SGPRs ----
    float cst = 0.0f;
    int shp[16];
    #pragma unroll
    for (int j = 0; j < 16; j++) shp[j] = 0;

    const float4* xp = reinterpret_cast<const float4*>(
        x + (size_t)b * TSTEPS * FEAT);

    // software pipeline: x_t in regs, x_{t+1} loads issued early
    float4 xc0 = xp[0], xc1 = xp[1], xc2 = xp[2], xc3 = xp[3];

    for (int t = 0; t < TSTEPS; t++) {
        float4 xn0, xn1, xn2, xn3;
        if (t + 1 < TSTEPS) {
            xn0 = xp[(t + 1) * 4 + 0];
            xn1 = xp[(t + 1) * 4 + 1];
            xn2 = xp[(t + 1) * 4 + 2];
            xn3 = xp[(t + 1) * 4 + 3];
        } else {
            xn0 = xn1 = xn2 = xn3 = make_float4(0.f, 0.f, 0.f, 0.f);
        }

        // pack x_t into f16x2 pairs (wave-uniform values)
        half2v xpk[FEAT / 2];
        xpk[0] = pkrtz(xc0.x, xc0.y);  xpk[1] = pkrtz(xc0.z, xc0.w);
        xpk[2] = pkrtz(xc1.x, xc1.y);  xpk[3] = pkrtz(xc1.z, xc1.w);
        xpk[4] = pkrtz(xc2.x, xc2.y);  xpk[5] = pkrtz(xc2.z, xc2.w);
        xpk[6] = pkrtz(xc3.x, xc3.y);  xpk[7] = pkrtz(xc3.z, xc3.w);

        // ---- gate pre-activations via dot2 (f16 mul, fp32 acc) ----
        float accA = bA, accB = bB;
        #pragma unroll
        for (int j = 0; j < FEAT / 2; j++) {
            accA = __builtin_amdgcn_fdot2(xpk[j], wW[0][j], accA, false);
            accB = __builtin_amdgcn_fdot2(xpk[j], wW[1][j], accB, false);
        }
        #pragma unroll
        for (int j = 0; j < HID / 2; j++) {
            half2v h2 = __builtin_bit_cast(half2v, shp[j]);
            accA = __builtin_amdgcn_fdot2(h2, wU[0][j], accA, false);
            accB = __builtin_amdgcn_fdot2(h2, wU[1][j], accB, false);
        }

        // ---- activations ----
        float a0 = fast_sigmoid(accA);            // i (low) / f (high)
        float s1 = fast_sigmoid(accB);
        float r1 = fmaxf(accB, 0.0f);
        float a1 = (lane < 32) ? r1 : s1;         // relu(cc) (low) / o (high)

        float f_s = __shfl_xor(a0, 32, 64);       // low lanes get sigmoid(f)
        float o_s = __shfl_xor(a1, 32, 64);       // low lanes get sigmoid(o)

        // c/h update (valid in low lanes; high lanes compute garbage, unused)
        float cn = fmaf(f_s, cst, a0 * a1);
        cst = cn;
        float hn = o_s * fmaxf(cn, 0.0f);

        // ---- distribute h: pack pairs, readlane to 16 uniform SGPRs ----
        float hx = __shfl_xor(hn, 1, 64);
        int pk = __builtin_bit_cast(int, pkrtz(hn, hx));  // even low lanes: (h[2j], h[2j+1])
        shp[0]  = __builtin_amdgcn_readlane(pk, 0);
        shp[1]  = __builtin_amdgcn_readlane(pk, 2);
        shp[2]  = __builtin_amdgcn_readlane(pk, 4);
        shp[3]  = __builtin_amdgcn_readlane(pk, 6);
        shp[4]  = __builtin_amdgcn_readlane(pk, 8);
        shp[5]  = __builtin_amdgcn_readlane(pk, 10);
        shp[6]  = __builtin_amdgcn_readlane(pk, 12);
        shp[7]  = __builtin_amdgcn_readlane(pk, 14);
        shp[8]  = __builtin_amdgcn_readlane(pk, 16);
        shp[9]  = __builtin_amdgcn_readlane(pk, 18);
        shp[10] = __builtin_amdgcn_readlane(pk, 20);
        shp[11] = __builtin_amdgcn_readlane(pk, 22);
        shp[12] = __builtin_amdgcn_readlane(pk, 24);
        shp[13] = __builtin_amdgcn_readlane(pk, 26);
        shp[14] = __builtin_amdgcn_readlane(pk, 28);
        shp[15] = __builtin_amdgcn_readlane(pk, 30);

        xc0 = xn0; xc1 = xn1; xc2 = xn2; xc3 = xn3;
    }

    // ---- heads: lane j < 60 computes output column j for this wave's batch ----
    if (lane < DOUT) {
        float s1 = b1[lane], s2 = b2[lane];
        #pragma unroll
        for (int j = 0; j < HID / 2; j++) {
            half2v h2  = __builtin_bit_cast(half2v, shp[j]);
            half2v w1p = pkrtz(W1[(2 * j) * DOUT + lane], W1[(2 * j + 1) * DOUT + lane]);
            half2v w2p = pkrtz(W2[(2 * j) * DOUT + lane], W2[(2 * j + 1) * DOUT + lane]);
            s1 = __builtin_amdgcn_fdot2(h2, w1p, s1, false);
            s2 = __builtin_amdgcn_fdot2(h2, w2p, s2, false);
        }
        out[(size_t)b * DOUT + lane] = s1;
        out[(size_t)BATCH * DOUT + (size_t)b * DOUT + lane] = s2;
    }
}

extern "C" void kernel_launch(void* const* d_in, const int* in_sizes, int n_in,
                              void* d_out, int out_size, void* d_ws, size_t ws_size,
                              hipStream_t stream) {
    const float* x  = (const float*)d_in[0];
    const float* W  = (const float*)d_in[1];
    const float* U  = (const float*)d_in[2];
    const float* bg = (const float*)d_in[3];
    const float* W1 = (const float*)d_in[4];
    const float* b1 = (const float*)d_in[5];
    const float* W2 = (const float*)d_in[6];
    const float* b2 = (const float*)d_in[7];
    float* out = (float*)d_out;

    dim3 grid(BATCH / WPB);   // 2048 blocks x 4 waves = 8192 waves (1 per batch elem)
    dim3 block(64 * WPB);
    lstm_fused<<<grid, block, 0, stream>>>(x, W, U, bg, W1, b1, W2, b2, out);
}

// Round 4
// 270.451 us; speedup vs baseline: 3.5097x; 3.5097x over previous
//
#include <hip/hip_runtime.h>

// Problem constants (match reference)
#define BATCH 8192
#define TSTEPS 200
#define FEAT 16
#define HID 32
#define GATES 128   // 4*HID, Keras order: i | f | cc | o
#define DOUT 60
#define ROWS 16     // batch rows per block (one MFMA M-tile)
#define HSTRIDE 40  // LDS h row stride in halves (80 B, padded: breaks row-parity conflicts)

typedef __fp16 half2v __attribute__((ext_vector_type(2)));
typedef __fp16 half8v __attribute__((ext_vector_type(8)));
typedef float  float4v __attribute__((ext_vector_type(4)));

__device__ __forceinline__ float fast_sigmoid(float v) {
    float e = __builtin_amdgcn_exp2f(v * -1.44269504088896340736f);
    return __builtin_amdgcn_rcpf(1.0f + e);
}

__device__ __forceinline__ half2v pkrtz(float a, float b) {
    return __builtin_amdgcn_cvt_pkrtz(a, b);
}

// MFMA-based persistent LSTM.
// Block = 128 threads = 2 waves, owns 16 batch rows.
// Wave w owns h-units [16w, 16w+16): gate column tiles at 16w + {0,32,64,96}.
// Per step: acc = bias; acc += x_t·W (K=16 zero-padded to 32); barrier;
//           acc += h·U (K=32); lane-local gate epilogue (i,f,cc,o all land in
//           the same lane for one (row,unit)); write h_{t+1} to the other LDS
//           buffer. One __syncthreads per step.
// Fragment layouts (gfx950, verified m89/m91/m120):
//   A[m][k]: m = lane&15, k = (lane>>4)*8 + j   (8 f16/lane)
//   B[k][n]: n = lane&15, k = (lane>>4)*8 + j   (8 f16/lane)
//   D[m][n]: n = lane&15, m = (lane>>4)*4 + r   (4 f32/lane)
__global__ __launch_bounds__(128, 1) void lstm_mfma(
    const float* __restrict__ x,    // [B, T, F]
    const float* __restrict__ W,    // [F, 128]
    const float* __restrict__ U,    // [H, 128]
    const float* __restrict__ bg,   // [128]
    const float* __restrict__ W1,   // [H, 60]
    const float* __restrict__ b1,   // [60]
    const float* __restrict__ W2,   // [H, 60]
    const float* __restrict__ b2,   // [60]
    float* __restrict__ out)        // [2 * B * 60] (long || lat)
{
    const int tid  = threadIdx.x;
    const int lane = tid & 63;
    const int w    = tid >> 6;      // unit-half: 0 or 1
    const int n16  = lane & 15;     // MFMA col (B/D) or row (A)
    const int g    = lane >> 4;     // k-quad
    const int b0   = blockIdx.x * ROWS;
    const int c0   = 16 * w;        // unit offset of this wave

    __shared__ __align__(16) __fp16 hbuf[2][ROWS * HSTRIDE];

    // ---- stationary B-frags: U (K=32) and zero-padded W (K=16 in k<16) ----
    half8v bU[4], bW[4];
    float  bias[4];
    #pragma unroll
    for (int t4 = 0; t4 < 4; t4++) {
        const int col = t4 * 32 + c0 + n16;   // gate column (i/f/cc/o tile)
        half8v u8, w8;
        #pragma unroll
        for (int j = 0; j < 8; j++) {
            const int k = g * 8 + j;
            u8[j] = (__fp16)U[k * GATES + col];
            w8[j] = (k < FEAT) ? (__fp16)W[k * GATES + col] : (__fp16)0.f;
        }
        bU[t4] = u8;
        bW[t4] = w8;
        bias[t4] = bg[col];
    }

    // zero h_0 buffer
    for (int i = tid; i < ROWS * HSTRIDE; i += 128) hbuf[0][i] = (__fp16)0.f;

    float cst[4] = {0.f, 0.f, 0.f, 0.f};   // cell state, lane-local (4 rows)

    // x A-frag source: lanes g<2 hold feats g*8..g*8+7 of row n16; g>=2 -> 0
    const float* xrow = x + (size_t)(b0 + n16) * TSTEPS * FEAT + g * 8;
    float4 xa = make_float4(0.f, 0.f, 0.f, 0.f), xb = xa;
    if (g < 2) {
        xa = *reinterpret_cast<const float4*>(xrow);
        xb = *reinterpret_cast<const float4*>(xrow + 4);
    }

    for (int t = 0; t < TSTEPS; t++) {
        // pack x_t A-frag
        union { half8v v; half2v h2[4]; } ax;
        ax.h2[0] = pkrtz(xa.x, xa.y);
        ax.h2[1] = pkrtz(xa.z, xa.w);
        ax.h2[2] = pkrtz(xb.x, xb.y);
        ax.h2[3] = pkrtz(xb.z, xb.w);

        // acc = bias ; acc += x_t·W  (independent of h -> before barrier)
        float4v acc[4];
        #pragma unroll
        for (int t4 = 0; t4 < 4; t4++) {
            float4v a = {bias[t4], bias[t4], bias[t4], bias[t4]};
            acc[t4] = __builtin_amdgcn_mfma_f32_16x16x32_f16(ax.v, bW[t4], a, 0, 0, 0);
        }

        // prefetch x_{t+1}
        if (t + 1 < TSTEPS && g < 2) {
            xa = *reinterpret_cast<const float4*>(xrow + (size_t)(t + 1) * FEAT);
            xb = *reinterpret_cast<const float4*>(xrow + (size_t)(t + 1) * FEAT + 4);
        }

        __syncthreads();   // h_t complete in hbuf[t&1] (also covers zero-init at t=0)

        // h_t A-frag: row n16, units g*8..g*8+7 (contiguous, 16B aligned)
        half8v ha = *reinterpret_cast<const half8v*>(
            &hbuf[t & 1][n16 * HSTRIDE + g * 8]);

        #pragma unroll
        for (int t4 = 0; t4 < 4; t4++)
            acc[t4] = __builtin_amdgcn_mfma_f32_16x16x32_f16(ha, bU[t4], acc[t4], 0, 0, 0);

        // ---- lane-local epilogue: this lane owns (rows g*4+r, unit c0+n16) ----
        __fp16* hw = &hbuf[(t + 1) & 1][0];
        #pragma unroll
        for (int r = 0; r < 4; r++) {
            float iv = fast_sigmoid(acc[0][r]);
            float fv = fast_sigmoid(acc[1][r]);
            float cc = acc[2][r];
            float ov = fast_sigmoid(acc[3][r]);
            float cn = fmaf(fv, cst[r], iv * fmaxf(cc, 0.f));
            cst[r] = cn;
            float hn = ov * fmaxf(cn, 0.f);
            hw[(g * 4 + r) * HSTRIDE + c0 + n16] = (__fp16)hn;
        }
    }

    __syncthreads();   // h_T complete in hbuf[0] (TSTEPS even)

    // ---- heads: out = h_T @ W1/W2 + b (fp32 math, h from LDS) ----
    const __fp16* hf = &hbuf[TSTEPS & 1][0];
    for (int idx = tid; idx < ROWS * DOUT; idx += 128) {
        const int row = idx / DOUT;
        const int d   = idx - row * DOUT;
        float s1 = b1[d], s2 = b2[d];
        #pragma unroll 8
        for (int k = 0; k < HID; k++) {
            float hv = (float)hf[row * HSTRIDE + k];
            s1 = fmaf(hv, W1[k * DOUT + d], s1);
            s2 = fmaf(hv, W2[k * DOUT + d], s2);
        }
        out[(size_t)(b0 + row) * DOUT + d] = s1;
        out[(size_t)BATCH * DOUT + (size_t)(b0 + row) * DOUT + d] = s2;
    }
}

extern "C" void kernel_launch(void* const* d_in, const int* in_sizes, int n_in,
                              void* d_out, int out_size, void* d_ws, size_t ws_size,
                              hipStream_t stream) {
    const float* x  = (const float*)d_in[0];
    const float* W  = (const float*)d_in[1];
    const float* U  = (const float*)d_in[2];
    const float* bg = (const float*)d_in[3];
    const float* W1 = (const float*)d_in[4];
    const float* b1 = (const float*)d_in[5];
    const float* W2 = (const float*)d_in[6];
    const float* b2 = (const float*)d_in[7];
    float* out = (float*)d_out;

    dim3 grid(BATCH / ROWS);   // 512 blocks x 2 waves = 1024 waves (1/SIMD)
    dim3 block(128);
    lstm_mfma<<<grid, block, 0, stream>>>(x, W, U, bg, W1, b1, W2, b2, out);
}